// Round 8
// baseline (29091.278 us; speedup 1.0000x reference)
//
#include <hip/hip_runtime.h>
#include <hip/hip_bf16.h>
#include <math.h>

#define E_ 7
#define B_ 50
#define T_ 100
#define D_ 128
#define A_ 32
#define L_ 256
#define H_ 1024
#define C_ 128
#define EB_ 350
#define TB_ 5000
#define SQRTH 0.31622776601683794f

typedef __attribute__((ext_vector_type(8))) short s8v;
typedef __attribute__((ext_vector_type(4))) float f32x4;
typedef _Float16 f16x2 __attribute__((ext_vector_type(2)));
typedef __hip_bfloat16 bf16;

#define MFMA __builtin_amdgcn_mfma_f32_16x16x32_bf16

__device__ __forceinline__ int lswz(int row, int ck) {
  return (((ck & ~7) | ((ck ^ row) & 7)) << 3);
}
__device__ __forceinline__ int swzE(int r, int col) {
  const int ck = col >> 3;
  return (((ck & ~7) | ((ck ^ r) & 7)) << 3) + (col & 7);
}
__device__ __forceinline__ f16x2 relu2(f16x2 t) {
#if __has_builtin(__builtin_elementwise_max)
  const f16x2 zz = {};
  return __builtin_elementwise_max(t, zz);
#else
  t[0] = t[0] > (_Float16)0 ? t[0] : (_Float16)0;
  t[1] = t[1] > (_Float16)0 ? t[1] : (_Float16)0;
  return t;
#endif
}
__device__ __forceinline__ float fdot2a(f16x2 a, f16x2 b, float c) {
#if __has_builtin(__builtin_amdgcn_fdot2)
  return __builtin_amdgcn_fdot2(a, b, c, false);
#else
  return c + (float)a[0] * (float)b[0] + (float)a[1] * (float)b[1];
#endif
}

struct BG {
  const bf16* A[8];
  const bf16* W[8];
  const float* bias[8];
  float* Cf[8];
  bf16* Cb[8];
};

// ---------------- bf16 MFMA GEMM (validated round 2) ----------------
template<int BM, int ACT, int OUT>
__global__ __launch_bounds__(256)
void bgemm(BG g, int M, int K, int lda, int ldw, int ldc) {
  __shared__ short As[BM * 64];
  __shared__ short Ws[128 * 64];
  const short* Ap = (const short*)g.A[blockIdx.z];
  const short* Wp = (const short*)g.W[blockIdx.z];
  const int bm = blockIdx.x * BM, bn = blockIdx.y * 128;
  const int tid = threadIdx.x;
  const int wv = tid >> 6, lane = tid & 63;
  const int wm0 = (wv >> 1) * (BM / 2), wn0 = (wv & 1) * 64;
  const int l15 = lane & 15, l4 = lane >> 4;
  constexpr int FM = BM / 32;
  constexpr int AI = BM / 32;
  f32x4 acc[FM][4] = {};
  for (int k0 = 0; k0 < K; k0 += 64) {
    s8v av[AI], wvv[4];
#pragma unroll
    for (int i = 0; i < AI; ++i) {
      const int c = tid + i * 256, r = c >> 3, ck = c & 7;
      s8v v = {};
      if (bm + r < M) v = *(const s8v*)(Ap + (size_t)(bm + r) * lda + k0 + ck * 8);
      av[i] = v;
    }
#pragma unroll
    for (int i = 0; i < 4; ++i) {
      const int c = tid + i * 256, r = c >> 3, ck = c & 7;
      wvv[i] = *(const s8v*)(Wp + (size_t)(bn + r) * ldw + k0 + ck * 8);
    }
    __syncthreads();
#pragma unroll
    for (int i = 0; i < AI; ++i) {
      const int c = tid + i * 256, r = c >> 3, ck = c & 7;
      *(s8v*)(As + r * 64 + ((ck ^ (r & 7)) << 3)) = av[i];
    }
#pragma unroll
    for (int i = 0; i < 4; ++i) {
      const int c = tid + i * 256, r = c >> 3, ck = c & 7;
      *(s8v*)(Ws + r * 64 + ((ck ^ (r & 7)) << 3)) = wvv[i];
    }
    __syncthreads();
#pragma unroll
    for (int ks = 0; ks < 2; ++ks) {
      s8v af[FM], bfr[4];
#pragma unroll
      for (int m = 0; m < FM; ++m) {
        const int r = wm0 + m * 16 + l15, ck = ks * 4 + l4;
        af[m] = *(const s8v*)(As + r * 64 + ((ck ^ (r & 7)) << 3));
      }
#pragma unroll
      for (int n = 0; n < 4; ++n) {
        const int r = wn0 + n * 16 + l15, ck = ks * 4 + l4;
        bfr[n] = *(const s8v*)(Ws + r * 64 + ((ck ^ (r & 7)) << 3));
      }
#pragma unroll
      for (int m = 0; m < FM; ++m)
#pragma unroll
        for (int n = 0; n < 4; ++n)
          acc[m][n] = MFMA(af[m], bfr[n], acc[m][n], 0, 0, 0);
    }
    __syncthreads();
  }
  const float* bias = g.bias[blockIdx.z];
  float* Cf = g.Cf[blockIdx.z];
  bf16* Cb = g.Cb[blockIdx.z];
#pragma unroll
  for (int n = 0; n < 4; ++n) {
    const int col = bn + wn0 + n * 16 + l15;
    const float bv = bias ? bias[col] : 0.f;
#pragma unroll
    for (int m = 0; m < FM; ++m) {
#pragma unroll
      for (int j = 0; j < 4; ++j) {
        const int row = bm + wm0 + m * 16 + l4 * 4 + j;
        if (row < M) {
          float v = acc[m][n][j] + bv;
          if (ACT == 1) v = fmaxf(v, 0.f);
          if (ACT == 2) v = tanhf(v);
          if (OUT == 0) Cf[(size_t)row * ldc + col] = v;
          if (OUT == 1) Cb[(size_t)row * ldc + col] = __float2bfloat16(v);
        }
      }
    }
  }
}

// ---------------- conversions / packing ----------------
__global__ __launch_bounds__(256)
void cvtT_kernel(const float* __restrict__ src, bf16* __restrict__ dst,
                 int K, int N, long ss, long ds) {
  __shared__ float t[32][33];
  src += (size_t)blockIdx.z * ss;
  dst += (size_t)blockIdx.z * ds;
  const int n0 = blockIdx.x * 32, k0 = blockIdx.y * 32;
  const int tx = threadIdx.x & 31, ty = threadIdx.x >> 5;
#pragma unroll
  for (int i = 0; i < 4; ++i)
    t[ty + 8 * i][tx] = src[(size_t)(k0 + ty + 8 * i) * N + n0 + tx];
  __syncthreads();
#pragma unroll
  for (int i = 0; i < 4; ++i)
    dst[(size_t)(n0 + ty + 8 * i) * K + k0 + tx] = __float2bfloat16(t[tx][ty + 8 * i]);
}

struct B4 { bf16 a, b, c, d; };
__global__ __launch_bounds__(256)
void cvt_kernel(const float* __restrict__ s, bf16* __restrict__ d, int n4) {
  const int i = blockIdx.x * 256 + threadIdx.x;
  if (i < n4) {
    const float4 v = ((const float4*)s)[i];
    B4 o = {__float2bfloat16(v.x), __float2bfloat16(v.y),
            __float2bfloat16(v.z), __float2bfloat16(v.w)};
    ((B4*)d)[i] = o;
  }
}

// pack fp32 [K][N] row-major -> bf16 fragment-major [nt][kt][lane][8]
__global__ __launch_bounds__(256)
void packW(const float* __restrict__ src, bf16* __restrict__ dst, int K, int N) {
  const int idx = blockIdx.x * 256 + threadIdx.x;
  if (idx >= K * N) return;
  const int k = idx / N, n = idx - k * N;
  const size_t fo = ((size_t)(n >> 4) * (K >> 5) + (k >> 5)) * 512 +
                    (((k >> 3) & 3) << 7) + ((n & 15) << 3) + (k & 7);
  dst[fo] = __float2bfloat16(src[idx]);
}

__global__ __launch_bounds__(256)
void packWz(const float* __restrict__ act_w, bf16* __restrict__ hi, bf16* __restrict__ lo) {
  const int idx = blockIdx.x * 256 + threadIdx.x;
  if (idx >= E_ * 65536) return;
  const int e = idx >> 16, rem = idx & 65535, k = rem >> 8, n = rem & 255;
  const float w = act_w[(size_t)e * 416 * 256 + (size_t)k * 256 + n];
  const bf16 h = __float2bfloat16(w);
  const size_t fo = (size_t)e * 65536 + ((size_t)(n >> 4) * 8 + (k >> 5)) * 512 +
                    (((k >> 3) & 3) << 7) + ((n & 15) << 3) + (k & 7);
  hi[fo] = h;
  lo[fo] = __float2bfloat16(w - __bfloat162float(h));
}

__global__ __launch_bounds__(256)
void ax_build(const float* __restrict__ actions, const float* __restrict__ xs,
              bf16* __restrict__ dst) {
  const int idx = blockIdx.x * 256 + threadIdx.x;
  if (idx >= E_ * TB_ * 192) return;
  const int k = idx % 192;
  const int r = (idx / 192) % TB_;
  const int e = idx / (192 * TB_);
  float v = 0.f;
  if (k < 32) v = actions[((size_t)e * TB_ + r) * A_ + k];
  else if (k < 160) v = xs[((size_t)e * TB_ + r) * D_ + (k - 32)];
  dst[idx] = __float2bfloat16(v);
}

__global__ __launch_bounds__(256)
void waxT_build(const float* __restrict__ act_w, bf16* __restrict__ dst) {
  const int idx = blockIdx.x * 256 + threadIdx.x;
  if (idx >= E_ * 256 * 192) return;
  const int k = idx % 192;
  const int n = (idx / 192) % 256;
  const int e = idx / (192 * 256);
  float v = (k < 160) ? act_w[(size_t)e * 416 * 256 + (size_t)(256 + k) * 256 + n] : 0.f;
  dst[idx] = __float2bfloat16(v);
}

// g weights -> [arr][hpair][l][2] fp16 (coalesced for lane=l)
__global__ __launch_bounds__(256)
void gpack2(const float* __restrict__ gw1, const float* __restrict__ gb1,
            const float* __restrict__ gw2, _Float16* __restrict__ dst) {
  const int idx = blockIdx.x * 256 + threadIdx.x;
  if (idx >= 3 * 512 * 256 * 2) return;
  const int i = idx & 1;
  const int l = (idx >> 1) & 255;
  const int hpg = (idx >> 9) & 511;
  const int arr = idx >> 18;
  const float* s = arr == 0 ? gw1 : (arr == 1 ? gb1 : gw2);
  dst[idx] = (_Float16)s[(size_t)l * 1024 + hpg * 2 + i];
}

// ---------------- q/KL (+z0 f32) ----------------
__global__ __launch_bounds__(256)
void qkl_kernel(const float* __restrict__ ctx, int rows, int row_off, int ctx_estride,
                const float* __restrict__ qw, const float* __restrict__ qb,
                const float* __restrict__ pm, const float* __restrict__ pl,
                const float* __restrict__ eps0, float* __restrict__ z0f,
                float* __restrict__ logqp) {
  __shared__ float cx[16][128];
  __shared__ float red[16];
  const int e = blockIdx.y;
  const int r0 = blockIdx.x * 16;
  const int tid = threadIdx.x;
  {
    const int r = tid >> 4, c = (tid & 15) * 8;
    float4 v0 = make_float4(0.f, 0.f, 0.f, 0.f), v1 = v0;
    if (r0 + r < rows) {
      const float* src = ctx + (size_t)e * ctx_estride + (size_t)(r0 + r) * C_ + c;
      v0 = *(const float4*)src;
      v1 = *(const float4*)(src + 4);
    }
    *(float4*)&cx[r][c] = v0;
    *(float4*)&cx[r][c + 4] = v1;
  }
  if (tid < 16) red[tid] = 0.f;
  __syncthreads();
  const int j = tid;
  const float* w = qw + (size_t)e * C_ * 512;
  float am_[16] = {};
  float al_[16] = {};
  for (int k0 = 0; k0 < C_; k0 += 4) {
    float wm[4], wl[4];
#pragma unroll
    for (int q = 0; q < 4; ++q) {
      wm[q] = w[(size_t)(k0 + q) * 512 + j];
      wl[q] = w[(size_t)(k0 + q) * 512 + 256 + j];
    }
#pragma unroll
    for (int r = 0; r < 16; ++r) {
      const float4 cv = *(const float4*)&cx[r][k0];
      const float cc[4] = {cv.x, cv.y, cv.z, cv.w};
#pragma unroll
      for (int q = 0; q < 4; ++q) {
        am_[r] = fmaf(cc[q], wm[q], am_[r]);
        al_[r] = fmaf(cc[q], wl[q], al_[r]);
      }
    }
  }
  const float qbm = qb[(size_t)e * 512 + j];
  const float qbl = qb[(size_t)e * 512 + 256 + j];
  const float pmv = pm[(size_t)e * L_ + j];
  const float plv = pl[(size_t)e * L_ + j];
  const float inv2e = 0.5f * expf(-2.f * plv);
#pragma unroll
  for (int r = 0; r < 16; ++r) {
    float kl = 0.f;
    if (r0 + r < rows) {
      const float qm_ = am_[r] + qbm;
      const float ql_ = al_[r] + qbl;
      const float dm = qm_ - pmv;
      kl = plv - ql_ + (expf(2.f * ql_) + dm * dm) * inv2e - 0.5f;
      const int gi = row_off + r0 + r;
      if (gi < B_) {
        const size_t zi = ((size_t)e * B_ + gi) * L_ + j;
        z0f[zi] = qm_ + expf(ql_) * eps0[zi];
      }
    }
    for (int off = 32; off; off >>= 1) kl += __shfl_xor(kl, off, 64);
    if ((tid & 63) == 0) atomicAdd(&red[r], kl);
  }
  __syncthreads();
  if (tid < 16 && r0 + tid < rows) atomicAdd(&logqp[e], red[tid] * (1.0f / B_));
}

// ---------------- the whole scan: 28 independent WGs ----------------
struct SC {
  const bf16 *wzh, *wzl, *w1f, *w2f, *w3f;
  const _Float16* gpk;
  const float *fb1, *hb1, *fb2, *hb2, *fb3, *hb3, *gb2;
  const float *axw, *dw, *z0f;
  bf16* zs_bf;
  float* logqp;
};

template<int KT, int NT>
__device__ __forceinline__ void mm(const short* As_, int astride, const short* Bf,
                                   int ngBase, int lane, f32x4* acc) {
  const int l15 = lane & 15, l4 = lane >> 4;
#pragma unroll 4
  for (int kt = 0; kt < KT; ++kt) {
    const s8v av = *(const s8v*)(As_ + l15 * astride + lswz(l15, kt * 4 + l4));
#pragma unroll
    for (int nt = 0; nt < NT; ++nt) {
      const s8v bv = *(const s8v*)(Bf + ((size_t)((ngBase + nt) * KT + kt)) * 512 + lane * 8);
      acc[nt] = MFMA(av, bv, acc[nt], 0, 0, 0);
    }
  }
}

__global__ __launch_bounds__(1024, 4) void scan28(SC a) {
  __shared__ float zst[16 * 256];
  __shared__ float zP[16 * 256];
  __shared__ float fvb[16 * 256];
  __shared__ float gvt[16 * 256];
  __shared__ short zPb[16 * 256];
  __shared__ short zh_[16 * 256];
  __shared__ short zl_[16 * 256];
  __shared__ short S[16 * 1024];
  __shared__ short S2[16 * 1024];
  const int wg = blockIdx.x;
  const int e = wg >> 2, q = wg & 3;
  const int nr = (q < 2) ? 13 : 12;
  const int b0 = (q < 2) ? q * 13 : 26 + (q - 2) * 12;
  const int tid = threadIdx.x;
  const int wave = tid >> 6, lane = tid & 63, l15 = lane & 15, l4 = lane >> 4;
  const int mw = wave & 7;
  const bool isM = wave < 8;
  const int gt = (wave - 8) * 64 + lane;  // 0..511 for g-waves
  const int gl = gt >> 1, ghh = gt & 1;

  for (int i = tid; i < 4096; i += 1024) {
    const int r = i >> 8, c = i & 255;
    zst[i] = (r < nr) ? a.z0f[(size_t)((e * 50 + b0 + r) * 256 + c)] : 0.f;
  }
  float lrA = 0.f;
  const short* wzhE = (const short*)a.wzh + (size_t)e * 65536;
  const short* wzlE = (const short*)a.wzl + (size_t)e * 65536;
  const short* w1p = (const short*)a.w1f;
  const short* w2p = (const short*)a.w2f;
  const short* w3p = (const short*)a.w3f;

  for (int t = 0; t < T_; ++t) {
    __syncthreads();  // prev epi (or init) -> zhl build
    for (int i = tid; i < 4096; i += 1024) {
      const int r = i >> 8, c = i & 255;
      const float f = zst[i];
      const bf16 h = __float2bfloat16(f);
      const bf16 lo = __float2bfloat16(f - __bfloat162float(h));
      const int eo = r * 256 + swzE(r, c);
      *(bf16*)&zh_[eo] = h;
      *(bf16*)&zl_[eo] = lo;
    }
    __syncthreads();  // zhl -> act
    {  // act: all 16 waves, one 16-col tile each
      f32x4 acc = {};
#pragma unroll
      for (int kt = 0; kt < 8; ++kt) {
        const s8v ah = *(const s8v*)(zh_ + l15 * 256 + lswz(l15, kt * 4 + l4));
        const s8v al = *(const s8v*)(zl_ + l15 * 256 + lswz(l15, kt * 4 + l4));
        const size_t bo = ((size_t)(wave * 8 + kt)) * 512 + lane * 8;
        const s8v bh = *(const s8v*)(wzhE + bo);
        const s8v bl = *(const s8v*)(wzlE + bo);
        acc = MFMA(ah, bh, acc, 0, 0, 0);
        acc = MFMA(al, bh, acc, 0, 0, 0);
        acc = MFMA(ah, bl, acc, 0, 0, 0);
      }
      const int col = wave * 16 + l15;
#pragma unroll
      for (int j = 0; j < 4; ++j) {
        const int r = l4 * 4 + j;
        float v = 0.f;
        if (r < nr)
          v = acc[j] + a.axw[((size_t)(e * TB_) + t * 50 + b0 + r) * 256 + col];
        zP[r * 256 + col] = v;
        *(bf16*)&zPb[r * 256 + swzE(r, col)] = __float2bfloat16(v);
      }
    }
    __syncthreads();  // act -> interval 1

    f16x2 z2g[13];
    float ga[13];
    if (!isM) {
#pragma unroll
      for (int r = 0; r < 13; ++r) {
        const _Float16 zh2 = (_Float16)zP[r * 256 + gl];
        z2g[r] = f16x2{zh2, zh2};
        ga[r] = 0.f;
      }
    }
    auto gchunk = [&](int h0, int h1) {
      for (int hp = h0; hp < h1; ++hp) {
        const size_t o = ((size_t)(ghh * 256 + hp)) * 512 + gl * 2;
        const f16x2 w1 = *(const f16x2*)(a.gpk + o);
        const f16x2 b1 = *(const f16x2*)(a.gpk + 262144 + o);
        const f16x2 w2 = *(const f16x2*)(a.gpk + 524288 + o);
#pragma unroll
        for (int r = 0; r < 13; ++r)
          ga[r] = fdot2a(relu2(z2g[r] * w1 + b1), w2, ga[r]);
      }
    };

    // interval 1: L1f | g
    if (isM) {
#pragma unroll
      for (int ph = 0; ph < 2; ++ph) {
        f32x4 acc[4] = {};
        mm<8, 4>(zPb, 256, w1p, mw * 8 + ph * 4, lane, acc);
#pragma unroll
        for (int nt = 0; nt < 4; ++nt) {
          const int col = (mw * 8 + ph * 4 + nt) * 16 + l15;
          const float bv = a.fb1[col];
#pragma unroll
          for (int j = 0; j < 4; ++j) {
            const int r = l4 * 4 + j;
            *(bf16*)&S[r * 1024 + swzE(r, col)] =
                __float2bfloat16(fmaxf(acc[nt][j] + bv, 0.f));
          }
        }
      }
    } else gchunk(0, 24);
    __syncthreads();
    // interval 2: L2f | g
    if (isM) {
#pragma unroll
      for (int ph = 0; ph < 2; ++ph) {
        f32x4 acc[4] = {};
        mm<32, 4>(S, 1024, w2p, mw * 8 + ph * 4, lane, acc);
#pragma unroll
        for (int nt = 0; nt < 4; ++nt) {
          const int col = (mw * 8 + ph * 4 + nt) * 16 + l15;
          const float bv = a.fb2[col];
#pragma unroll
          for (int j = 0; j < 4; ++j) {
            const int r = l4 * 4 + j;
            *(bf16*)&S2[r * 1024 + swzE(r, col)] =
                __float2bfloat16(tanhf(acc[nt][j] + bv));
          }
        }
      }
    } else gchunk(24, 104);
    __syncthreads();
    // interval 3: L3f -> fvb | g
    if (isM) {
      f32x4 acc[2] = {};
      mm<32, 2>(S2, 1024, w3p, mw * 2, lane, acc);
#pragma unroll
      for (int nt = 0; nt < 2; ++nt) {
        const int col = (mw * 2 + nt) * 16 + l15;
        const float bv = a.fb3[col];
#pragma unroll
        for (int j = 0; j < 4; ++j)
          fvb[(l4 * 4 + j) * 256 + col] = acc[nt][j] + bv;
      }
    } else gchunk(104, 128);
    __syncthreads();
    // interval 4: L1h | g
    if (isM) {
#pragma unroll
      for (int ph = 0; ph < 2; ++ph) {
        f32x4 acc[4] = {};
        mm<8, 4>(zPb, 256, w1p, 64 + mw * 8 + ph * 4, lane, acc);
#pragma unroll
        for (int nt = 0; nt < 4; ++nt) {
          const int col = (mw * 8 + ph * 4 + nt) * 16 + l15;
          const float bv = a.hb1[col];
#pragma unroll
          for (int j = 0; j < 4; ++j) {
            const int r = l4 * 4 + j;
            *(bf16*)&S[r * 1024 + swzE(r, col)] =
                __float2bfloat16(fmaxf(acc[nt][j] + bv, 0.f));
          }
        }
      }
    } else gchunk(128, 152);
    __syncthreads();
    // interval 5: L2h | g
    if (isM) {
#pragma unroll
      for (int ph = 0; ph < 2; ++ph) {
        f32x4 acc[4] = {};
        mm<32, 4>(S, 1024, w2p, 64 + mw * 8 + ph * 4, lane, acc);
#pragma unroll
        for (int nt = 0; nt < 4; ++nt) {
          const int col = (mw * 8 + ph * 4 + nt) * 16 + l15;
          const float bv = a.hb2[col];
#pragma unroll
          for (int j = 0; j < 4; ++j) {
            const int r = l4 * 4 + j;
            *(bf16*)&S2[r * 1024 + swzE(r, col)] =
                __float2bfloat16(tanhf(acc[nt][j] + bv));
          }
        }
      }
    } else gchunk(152, 232);
    __syncthreads();
    // interval 6: L3h (acc kept) | g finish + gvt write
    f32x4 acc3[2] = {};
    if (isM) {
      mm<32, 2>(S2, 1024, w3p, 16 + mw * 2, lane, acc3);
    } else {
      gchunk(232, 256);
#pragma unroll
      for (int r = 0; r < 13; ++r) {
        const float v = ga[r] + __shfl_xor(ga[r], 1, 64);
        if (ghh == 0) gvt[r * 256 + gl] = v + a.gb2[gl];
      }
    }
    __syncthreads();
    // epilogue: waves 0-7
    if (isM) {
#pragma unroll
      for (int nt = 0; nt < 2; ++nt) {
        const int col = (mw * 2 + nt) * 16 + l15;
        const float hb = a.hb3[col];
#pragma unroll
        for (int j = 0; j < 4; ++j) {
          const int r = l4 * 4 + j;
          if (r < nr) {
            const float fv = fvb[r * 256 + col];
            const float hv = acc3[nt][j] + hb;
            const float gv = gvt[r * 256 + col];
            const float u = (fv - hv) / gv;
            lrA += u * u;
            const float zn = zP[r * 256 + col] + 0.1f * fv +
                gv * (SQRTH * a.dw[(size_t)t * (EB_ * 256) +
                                   (size_t)((e * 50 + b0 + r) * 256 + col)]);
            zst[r * 256 + col] = zn;
            a.zs_bf[((size_t)(e * TB_) + t * 50 + b0 + r) * 256 + col] =
                __float2bfloat16(zn);
          }
        }
      }
    }
  }
  // lr reduction: one atomic per block
  __syncthreads();
  float v = lrA;
#pragma unroll
  for (int o = 32; o; o >>= 1) v += __shfl_xor(v, o, 64);
  if (lane == 0) gvt[wave] = v;
  __syncthreads();
  if (tid == 0) {
    float s = 0.f;
    for (int w = 0; w < 16; ++w) s += gvt[w];
    atomicAdd(&a.logqp[e], 0.001f * s);  // 0.5 * H_STEP / B
  }
}

__global__ void init_kernel(float* logqp) {
  if (threadIdx.x < E_) logqp[threadIdx.x] = 0.f;
}

extern "C" void kernel_launch(void* const* d_in, const int* in_sizes, int n_in,
                              void* d_out, int out_size, void* d_ws, size_t ws_size,
                              hipStream_t stream) {
  (void)in_sizes; (void)n_in; (void)out_size;
  const float* enc_w1 = (const float*)d_in[0];
  const float* enc_b1 = (const float*)d_in[1];
  const float* enc_w2 = (const float*)d_in[2];
  const float* enc_b2 = (const float*)d_in[3];
  const float* enc_w3 = (const float*)d_in[4];
  const float* enc_b3 = (const float*)d_in[5];
  const float* qz0_w  = (const float*)d_in[6];
  const float* qz0_b  = (const float*)d_in[7];
  const float* act_w  = (const float*)d_in[8];
  const float* act_b  = (const float*)d_in[9];
  const float* proj_w1 = (const float*)d_in[10];
  const float* proj_b1 = (const float*)d_in[11];
  const float* proj_w2 = (const float*)d_in[12];
  const float* proj_b2 = (const float*)d_in[13];
  const float* proj_w3 = (const float*)d_in[14];
  const float* proj_b3 = (const float*)d_in[15];
  const float* f_w1 = (const float*)d_in[16];
  const float* f_b1 = (const float*)d_in[17];
  const float* f_w2 = (const float*)d_in[18];
  const float* f_b2 = (const float*)d_in[19];
  const float* f_w3 = (const float*)d_in[20];
  const float* f_b3 = (const float*)d_in[21];
  const float* h_w1 = (const float*)d_in[22];
  const float* h_b1 = (const float*)d_in[23];
  const float* h_w2 = (const float*)d_in[24];
  const float* h_b2 = (const float*)d_in[25];
  const float* h_w3 = (const float*)d_in[26];
  const float* h_b3 = (const float*)d_in[27];
  const float* g_w1 = (const float*)d_in[28];
  const float* g_b1 = (const float*)d_in[29];
  const float* g_w2 = (const float*)d_in[30];
  const float* g_b2 = (const float*)d_in[31];
  const float* pz0_mean   = (const float*)d_in[32];
  const float* pz0_logstd = (const float*)d_in[33];
  const float* xs      = (const float*)d_in[34];
  const float* actions = (const float*)d_in[35];
  const float* eps_z0  = (const float*)d_in[36];
  const float* dw      = (const float*)d_in[37];

  float* out = (float*)d_out;
  float* logqp = out;
  float* pred = out + E_;

  char* base = (char*)d_ws;
  size_t off = 0;
  auto alloc = [&](size_t bytes) {
    void* p = base + off;
    off = (off + bytes + 255) & ~(size_t)255;
    return p;
  };
  float* z0f   = (float*)alloc((size_t)EB_ * 256 * 4);
  bf16* zs_bf  = (bf16*)alloc((size_t)E_ * T_ * B_ * 256 * 2);
  float* axw   = (float*)alloc((size_t)E_ * TB_ * 256 * 4);
  bf16* ax_bf  = (bf16*)alloc((size_t)E_ * TB_ * 192 * 2);
  bf16* waxT   = (bf16*)alloc((size_t)E_ * 256 * 192 * 2);
  bf16* wzh    = (bf16*)alloc((size_t)E_ * 65536 * 2);
  bf16* wzl    = (bf16*)alloc((size_t)E_ * 65536 * 2);
  bf16* w1f    = (bf16*)alloc((size_t)2048 * 256 * 2);
  bf16* w2f    = (bf16*)alloc((size_t)2048 * 1024 * 2);
  bf16* w3f    = (bf16*)alloc((size_t)512 * 1024 * 2);
  _Float16* gpk = (_Float16*)alloc((size_t)3 * 512 * 256 * 2 * 2);
  bf16* xs_bf  = (bf16*)alloc((size_t)E_ * TB_ * D_ * 2);
  bf16* ew1T = (bf16*)alloc((size_t)E_ * D_ * H_ * 2);
  bf16* ew2T = (bf16*)alloc((size_t)E_ * H_ * H_ * 2);
  bf16* ew3T = (bf16*)alloc((size_t)E_ * H_ * C_ * 2);
  bf16* pw1T = (bf16*)alloc((size_t)E_ * L_ * H_ * 2);
  bf16* pw2T = (bf16*)alloc((size_t)E_ * H_ * H_ * 2);
  bf16* pw3T = (bf16*)alloc((size_t)E_ * H_ * D_ * 2);
  const size_t per_row = (size_t)E_ * (H_ * 2 * 2 + C_ * 4);
  size_t remain = (ws_size > off + 4096) ? (ws_size - off - 4096) : 0;
  int CH = (int)(remain / per_row);
  if (CH > 2500) CH = 2500;
  if (CH < 64) CH = 64;
  bf16* bufA = (bf16*)alloc((size_t)E_ * CH * H_ * 2);
  bf16* bufB = (bf16*)alloc((size_t)E_ * CH * H_ * 2);
  float* bufC = (float*)alloc((size_t)E_ * CH * C_ * 4);

  init_kernel<<<dim3(1), dim3(64), 0, stream>>>(logqp);

  const dim3 cb256(256);
  cvt_kernel<<<dim3((E_ * TB_ * D_ / 4 + 255) / 256), cb256, 0, stream>>>(xs, xs_bf, E_ * TB_ * D_ / 4);
  cvtT_kernel<<<dim3(H_ / 32, D_ / 32, E_), cb256, 0, stream>>>(enc_w1, ew1T, D_, H_, (long)D_ * H_, (long)D_ * H_);
  cvtT_kernel<<<dim3(H_ / 32, H_ / 32, E_), cb256, 0, stream>>>(enc_w2, ew2T, H_, H_, (long)H_ * H_, (long)H_ * H_);
  cvtT_kernel<<<dim3(C_ / 32, H_ / 32, E_), cb256, 0, stream>>>(enc_w3, ew3T, H_, C_, (long)H_ * C_, (long)H_ * C_);
  cvtT_kernel<<<dim3(H_ / 32, L_ / 32, E_), cb256, 0, stream>>>(proj_w1, pw1T, L_, H_, (long)L_ * H_, (long)L_ * H_);
  cvtT_kernel<<<dim3(H_ / 32, H_ / 32, E_), cb256, 0, stream>>>(proj_w2, pw2T, H_, H_, (long)H_ * H_, (long)H_ * H_);
  cvtT_kernel<<<dim3(D_ / 32, H_ / 32, E_), cb256, 0, stream>>>(proj_w3, pw3T, H_, D_, (long)H_ * D_, (long)H_ * D_);
  ax_build<<<dim3((E_ * TB_ * 192 + 255) / 256), cb256, 0, stream>>>(actions, xs, ax_bf);
  waxT_build<<<dim3((E_ * 256 * 192 + 255) / 256), cb256, 0, stream>>>(act_w, waxT);
  packWz<<<dim3((E_ * 65536 + 255) / 256), cb256, 0, stream>>>(act_w, wzh, wzl);
  packW<<<dim3((256 * 1024 + 255) / 256), cb256, 0, stream>>>(f_w1, w1f, 256, 1024);
  packW<<<dim3((256 * 1024 + 255) / 256), cb256, 0, stream>>>(h_w1, w1f + (size_t)1024 * 256, 256, 1024);
  packW<<<dim3((1024 * 1024 + 255) / 256), cb256, 0, stream>>>(f_w2, w2f, 1024, 1024);
  packW<<<dim3((1024 * 1024 + 255) / 256), cb256, 0, stream>>>(h_w2, w2f + (size_t)1024 * 1024, 1024, 1024);
  packW<<<dim3((1024 * 256 + 255) / 256), cb256, 0, stream>>>(f_w3, w3f, 1024, 256);
  packW<<<dim3((1024 * 256 + 255) / 256), cb256, 0, stream>>>(h_w3, w3f + (size_t)256 * 1024, 1024, 256);
  gpack2<<<dim3((3 * 512 * 256 * 2 + 255) / 256), cb256, 0, stream>>>(g_w1, g_b1, g_w2, gpk);

  BG g;
  for (int e = 0; e < E_; ++e) {
    g.A[e] = ax_bf + (size_t)e * TB_ * 192;
    g.W[e] = waxT + (size_t)e * 256 * 192;
    g.bias[e] = act_b + (size_t)e * 256;
    g.Cf[e] = axw + (size_t)e * TB_ * 256;
  }
  bgemm<128, 0, 0><<<dim3((TB_ + 127) / 128, 2, E_), 256, 0, stream>>>(g, TB_, 192, 192, 192, 256);

  // ---- Phase A: encoder + q/KL (+z0 f32) ----
  for (int c = 0; c < TB_; c += CH) {
    const int rows = (TB_ - c < CH) ? (TB_ - c) : CH;
    const int mt = (rows + 127) / 128;
    for (int e = 0; e < E_; ++e) {
      g.A[e] = xs_bf + ((size_t)e * TB_ + c) * D_;
      g.W[e] = ew1T + (size_t)e * D_ * H_;
      g.bias[e] = enc_b1 + (size_t)e * H_;
      g.Cb[e] = bufA + (size_t)e * CH * H_;
    }
    bgemm<128, 1, 1><<<dim3(mt, H_ / 128, E_), 256, 0, stream>>>(g, rows, D_, D_, D_, H_);
    for (int e = 0; e < E_; ++e) {
      g.A[e] = bufA + (size_t)e * CH * H_;
      g.W[e] = ew2T + (size_t)e * H_ * H_;
      g.bias[e] = enc_b2 + (size_t)e * H_;
      g.Cb[e] = bufB + (size_t)e * CH * H_;
    }
    bgemm<128, 1, 1><<<dim3(mt, H_ / 128, E_), 256, 0, stream>>>(g, rows, H_, H_, H_, H_);
    for (int e = 0; e < E_; ++e) {
      g.A[e] = bufB + (size_t)e * CH * H_;
      g.W[e] = ew3T + (size_t)e * H_ * C_;
      g.bias[e] = enc_b3 + (size_t)e * C_;
      g.Cf[e] = bufC + (size_t)e * CH * C_;
    }
    bgemm<128, 0, 0><<<dim3(mt, C_ / 128, E_), 256, 0, stream>>>(g, rows, H_, H_, H_, C_);
    qkl_kernel<<<dim3((rows + 15) / 16, E_), 256, 0, stream>>>(
        bufC, rows, c, CH * C_, qz0_w, qz0_b, pz0_mean, pz0_logstd, eps_z0,
        z0f, logqp);
  }

  // ---- Scan: one kernel, 28 independent WGs ----
  SC sc;
  sc.wzh = wzh; sc.wzl = wzl; sc.w1f = w1f; sc.w2f = w2f; sc.w3f = w3f;
  sc.gpk = gpk;
  sc.fb1 = f_b1; sc.hb1 = h_b1; sc.fb2 = f_b2; sc.hb2 = h_b2;
  sc.fb3 = f_b3; sc.hb3 = h_b3; sc.gb2 = g_b2;
  sc.axw = axw; sc.dw = dw; sc.z0f = z0f;
  sc.zs_bf = zs_bf; sc.logqp = logqp;
  scan28<<<dim3(28), dim3(1024), 0, stream>>>(sc);

  // ---- Projector ----
  for (int c = 0; c < TB_; c += CH) {
    const int rows = (TB_ - c < CH) ? (TB_ - c) : CH;
    const int mt = (rows + 127) / 128;
    for (int e = 0; e < E_; ++e) {
      g.A[e] = zs_bf + ((size_t)e * T_ * B_ + c) * L_;
      g.W[e] = pw1T + (size_t)e * L_ * H_;
      g.bias[e] = proj_b1 + (size_t)e * H_;
      g.Cb[e] = bufA + (size_t)e * CH * H_;
    }
    bgemm<128, 2, 1><<<dim3(mt, H_ / 128, E_), 256, 0, stream>>>(g, rows, L_, L_, L_, H_);
    for (int e = 0; e < E_; ++e) {
      g.A[e] = bufA + (size_t)e * CH * H_;
      g.W[e] = pw2T + (size_t)e * H_ * H_;
      g.bias[e] = proj_b2 + (size_t)e * H_;
      g.Cb[e] = bufB + (size_t)e * CH * H_;
    }
    bgemm<128, 2, 1><<<dim3(mt, H_ / 128, E_), 256, 0, stream>>>(g, rows, H_, H_, H_, H_);
    for (int e = 0; e < E_; ++e) {
      g.A[e] = bufB + (size_t)e * CH * H_;
      g.W[e] = pw3T + (size_t)e * H_ * D_;
      g.bias[e] = proj_b3 + (size_t)e * D_;
      g.Cf[e] = pred + ((size_t)e * TB_ + c) * D_;
    }
    bgemm<128, 0, 0><<<dim3(mt, D_ / 128, E_), 256, 0, stream>>>(g, rows, H_, H_, H_, D_);
  }
}